// Round 16
// baseline (102.509 us; speedup 1.0000x reference)
//
#include <hip/hip_runtime.h>

// YOLO NMS post-processing, exact reimplementation of the JAX reference.
//  * valid = obj >= 0.8 -> ~2130 valid/image << TOPK=4096: top_k never drops
//    a valid det; invalid dets can neither suppress nor be kept.
//  * suppression requires cls_pred equality -> NMS decomposes into 8x80
//    independent per-(image,class) problems, ~27 boxes each (CAP=96 ~13sig).
//  * R10: per-cell membership via byte-class scan + ballot-compact; NMS fully
//    in wave registers (readlane/ballot, VALU pipe).
//  * Sync scoreboard (fused kernel dur): acquire-load poll no backoff = 85us
//    (storm); relaxed poll + backoff = 52us (stale per-XCD L2 until evict);
//    RMW poll + backoff = 63us (coherence-point RMW serialization).
//  * R15: producers release-add arrive[b]; LAST producer release-stores
//    ready[b] (own padded line); consumers poll ready[b] with acquire loads
//    + ~3us backoff. R15 BUG: sync[] zeroing used "tid < 512" in a 256-thread
//    block -> ready flags (indices 256..480) never zeroed -> 0xAA poison made
//    consumers skip the wait. R16: stride-loop zeroes all 16*DSTR ints.

#define NCH    85
#define NCLS   80
#define TOPK   4096
#define CAP    96
#define KBLK   64     // output chunks per image (64 * 64 slots = 4096)
#define RWAVES 8      // j-split waves per rank chunk
#define PBB    80     // phase-B producer blocks (8 cells each = 640 cells)
#define BPI    10     // producer blocks per image
#define DSTR   32     // sync[] stride in ints (128 B / line)

__device__ __forceinline__ float rlf(float v, int l) {
    return __uint_as_float(__builtin_amdgcn_readlane(__float_as_uint(v), l));
}
__device__ __forceinline__ int rli(int v, int l) {
    return __builtin_amdgcn_readlane(v, l);
}

// ---- K1: per-det score/cc (float2), class byte, corner float4; zero sync ---
__global__ void score_kernel(const float* __restrict__ det,
                             float2* __restrict__ A,
                             unsigned char* __restrict__ Cc,
                             float4* __restrict__ REC,
                             int* __restrict__ sync,
                             int N, int NP, int total) {
#pragma clang fp contract(off)   // corner math must match numpy f32 exactly
    if (blockIdx.x == 0)                      // zero ALL sync words (R16 fix)
        for (int s = threadIdx.x; s < 16 * DSTR; s += blockDim.x) sync[s] = 0;

    int w    = (blockIdx.x * blockDim.x + threadIdx.x) >> 6;
    int lane = threadIdx.x & 63;
    if (w >= total) return;
    const float* row = det + (size_t)w * NCH;
    int b = w / N, i = w - b * N;

    float obj = row[4];                       // broadcast load
    if (obj < 0.8f) {                         // CONF_THRES, wave-uniform
        if (lane == 0) Cc[(size_t)b * NP + i] = 0xFFu;
        return;
    }
    float va = row[lane];                                    // cols 0..63
    float vb = (lane < NCH - 64) ? row[64 + lane] : -1.0f;   // cols 64..84
    float bestv = -1.0f; int bestc = 1 << 30;
    if (lane >= 5) { bestv = va; bestc = lane - 5; }         // cls 0..58
    if (lane < NCH - 64) {
        int c2 = 59 + lane;                                  // cls 59..79
        if (vb > bestv || (vb == bestv && c2 < bestc)) { bestv = vb; bestc = c2; }
    }
    for (int m = 32; m >= 1; m >>= 1) {
        float ov = __shfl_xor(bestv, m);
        int   oc = __shfl_xor(bestc, m);
        if (ov > bestv || (ov == bestv && oc < bestc)) { bestv = ov; bestc = oc; }
    }
    float x  = rlf(va, 0), y  = rlf(va, 1);
    float bw = rlf(va, 2), bh = rlf(va, 3);
    if (lane == 0) {
        float hw = bw * 0.5f, hh = bh * 0.5f;                // w/2 exact
        A[(size_t)b * NP + i]  = make_float2(obj * bestv, bestv);
        Cc[(size_t)b * NP + i] = (unsigned char)bestc;
        REC[(size_t)w] = make_float4(x - hw, y - hh, x + hw, y + hh);
    }
}

// ---- K2: fused per-cell NMS (80 producer blocks) + rank-scatter (all) ------
// sync layout: arrive[b] at sync[b*DSTR], ready[b] at sync[(8+b)*DSTR].
__global__ void __launch_bounds__(512, 4) fused_kernel(
        const float2* __restrict__ A,
        const unsigned char* __restrict__ Cc,
        const float4* __restrict__ REC,
        float* __restrict__ kv,
        int*   __restrict__ kcnt,
        int*   __restrict__ sync,
        float* __restrict__ out,
        int N, int NT, int NP) {
#pragma clang fp contract(off)   // IoU math must be bit-identical to numpy f32
    const int bid  = blockIdx.x;
    const int tid  = threadIdx.x;
    const int lane = tid & 63;
    const int wid  = tid >> 6;                // 0..7

    __shared__ int   lidx[8][CAP];
    __shared__ int   tmp2[8][CAP];
    __shared__ int   off[NCLS];
    __shared__ float v[TOPK] __attribute__((aligned(16)));
    __shared__ int   part[RWAVES][64];

    // ================= phase B: one wave per (image,class) cell =============
    if (bid < PBB) {
        int cell = bid * 8 + wid;             // 640 cells exactly
        int b = cell / NCLS, c = cell % NCLS;
        unsigned long long mlt = (1ull << lane) - 1ull;

        // membership scan over byte classes (order-free; rank re-sorts)
        const unsigned char* Cb = Cc + (size_t)b * NP;
        int cnt = 0;
        uint4 q = *(const uint4*)(Cb + lane * 16);
        for (int t = 0; t < NT; t++) {
            uint4 qn;
            if (t + 1 < NT) qn = *(const uint4*)(Cb + (size_t)(t + 1) * 1024 + lane * 16);
            int i0 = t * 1024 + lane * 16;
            unsigned xs[4] = { q.x, q.y, q.z, q.w };
            unsigned mm = 0;
            #pragma unroll
            for (int kk = 0; kk < 16; kk++) {
                unsigned byte = (xs[kk >> 2] >> ((kk & 3) * 8)) & 0xFFu;
                if (byte == (unsigned)c && (i0 + kk) < N) mm |= 1u << kk;
            }
            if (__ballot(mm != 0)) {
                #pragma unroll
                for (int kk = 0; kk < 16; kk++) {
                    unsigned long long mk = __ballot((mm >> kk) & 1u);
                    if (mk) {
                        if ((mm >> kk) & 1u) {
                            int p = cnt + __popcll(mk & mlt);
                            if (p < CAP) lidx[wid][p] = i0 + kk;
                        }
                        cnt += __popcll(mk);
                    }
                }
            }
            q = qn;
        }
        int n = cnt < CAP ? cnt : CAP;
        if (n == 0) {
            if (lane == 0) kcnt[cell] = 0;
        } else {
            bool a0 = lane < n, a1 = lane + 64 < n;
            const float2* Ab = A + (size_t)b * NP;
            int id0 = a0 ? lidx[wid][lane]      : 0;
            int id1 = a1 ? lidx[wid][lane + 64] : 0;
            float s0 = a0 ? Ab[id0].x : 0.0f;
            float s1 = a1 ? Ab[id1].x : 0.0f;

            // rank by (score desc, idx asc) == top_k order within class
            int r0 = 0, r1 = 0;
            int m0 = n < 64 ? n : 64;
            for (int j = 0; j < m0; j++) {
                float sj = rlf(s0, j); int ij = rli(id0, j);
                r0 += (sj > s0) || (sj == s0 && ij < id0);
                r1 += (sj > s1) || (sj == s1 && ij < id1);
            }
            for (int j = 64; j < n; j++) {
                float sj = rlf(s1, j - 64); int ij = rli(id1, j - 64);
                r0 += (sj > s0) || (sj == s0 && ij < id0);
                r1 += (sj > s1) || (sj == s1 && ij < id1);
            }
            if (a0) tmp2[wid][r0] = id0;      // same-wave LDS, in-order
            if (a1) tmp2[wid][r1] = id1;
            int di0 = a0 ? tmp2[wid][lane]      : 0;
            int di1 = a1 ? tmp2[wid][lane + 64] : 0;

            // gather sorted records: cc + corners + area (exact ref op order)
            float scc = 0, x10 = 0, y10 = 0, x20 = 0, y20 = 0, ar0 = 0;
            if (a0) {
                scc = Ab[di0].y;
                float4 rc = REC[(size_t)b * N + di0];
                x10 = rc.x; y10 = rc.y; x20 = rc.z; y20 = rc.w;
                ar0 = (x20 - x10 + 1.0f) * (y20 - y10 + 1.0f);
            }
            float tcc = 0, x11 = 0, y11 = 0, x21 = 0, y21 = 0, ar1 = 0;
            if (a1) {
                tcc = Ab[di1].y;
                float4 rc = REC[(size_t)b * N + di1];
                x11 = rc.x; y11 = rc.y; x21 = rc.z; y21 = rc.w;
                ar1 = (x21 - x11 + 1.0f) * (y21 - y11 + 1.0f);
            }

            // column masks: bit i of col(j) = (iou(i,j) > thr), i < j
            unsigned long long col0 = 0, col1a = 0, col1b = 0;
            for (int i = 0; i < n; i++) {
                float ix1, iy1, ix2, iy2, iar;
                if (i < 64) {
                    ix1 = rlf(x10, i); iy1 = rlf(y10, i);
                    ix2 = rlf(x20, i); iy2 = rlf(y20, i); iar = rlf(ar0, i);
                } else {
                    ix1 = rlf(x11, i - 64); iy1 = rlf(y11, i - 64);
                    ix2 = rlf(x21, i - 64); iy2 = rlf(y21, i - 64); iar = rlf(ar1, i - 64);
                }
                if (lane > i && lane < n) {
                    float iw = fminf(ix2, x20) - fmaxf(ix1, x10) + 1.0f;
                    float ih = fminf(iy2, y20) - fmaxf(iy1, y10) + 1.0f;
                    iw = fmaxf(iw, 0.0f); ih = fmaxf(ih, 0.0f);
                    float inter = iw * ih;
                    float iou = inter / (iar + ar0 - inter + 1e-16f);
                    if (iou > 0.4f) col0 |= 1ull << i;        // NMS_THRES
                }
                if (n > 64) {
                    int j2 = lane + 64;
                    if (j2 > i && j2 < n) {
                        float iw = fminf(ix2, x21) - fmaxf(ix1, x11) + 1.0f;
                        float ih = fminf(iy2, y21) - fmaxf(iy1, y11) + 1.0f;
                        iw = fmaxf(iw, 0.0f); ih = fmaxf(ih, 0.0f);
                        float inter = iw * ih;
                        float iou = inter / (iar + ar1 - inter + 1e-16f);
                        if (iou > 0.4f) {
                            if (i < 64) col1a |= 1ull << i;
                            else        col1b |= 1ull << (i - 64);
                        }
                    }
                }
            }

            // greedy: alive rank ii suppresses later columns with its bit set
            bool sup0 = false, sup1 = false;
            for (int ii = 0; ii < n; ii++) {
                bool alive;
                if (ii < 64) alive = !((__ballot(sup0) >> ii) & 1ull);
                else         alive = !((__ballot(sup1) >> (ii - 64)) & 1ull);
                if (alive) {
                    if (ii < 64) {
                        sup0 = sup0 | (((col0  >> ii) & 1ull) != 0);
                        sup1 = sup1 | (((col1a >> ii) & 1ull) != 0);
                    } else {
                        sup1 = sup1 | (((col1b >> (ii - 64)) & 1ull) != 0);
                    }
                }
            }

            // emit kept cc (sorted order) into this cell's private segment
            unsigned long long alive0 = __ballot((!sup0) && a0);
            int kn0 = __popcll(alive0);
            unsigned long long alive1 = (n > 64) ? __ballot((!sup1) && a1) : 0ull;
            int kn = kn0 + __popcll(alive1);
            float* kvc = kv + (size_t)cell * CAP;
            if ((!sup0) && a0) kvc[__popcll(alive0 & mlt)] = scc;
            if ((!sup1) && a1) kvc[kn0 + __popcll(alive1 & mlt)] = tcc;
            if (lane == 0) kcnt[cell] = kn;
        }
        __syncthreads();                      // all 8 cells of block done
        if (tid == 0) {
            int img = bid / BPI;
            int old = __hip_atomic_fetch_add(&sync[img * DSTR], 1,
                                             __ATOMIC_ACQ_REL,
                                             __HIP_MEMORY_SCOPE_AGENT);
            if (old == BPI - 1)               // last producer of this image
                __hip_atomic_store(&sync[(8 + img) * DSTR], 1,
                                   __ATOMIC_RELEASE, __HIP_MEMORY_SCOPE_AGENT);
        }
    }

    // ================= phase C: rank-scatter (all 512 blocks) ===============
    int b     = bid / KBLK;
    int chunk = bid % KBLK;
    int i     = chunk * 64 + lane;

    // R15/R16: poll single-writer ready flag with ACQUIRE LOADS + ~3us
    // backoff. Acquire loads are serviced fresh (coherence point) and reads
    // parallelize (no RMW ownership queue).
    if (tid == 0) {
        while (__hip_atomic_load(&sync[(8 + b) * DSTR], __ATOMIC_ACQUIRE,
                                 __HIP_MEMORY_SCOPE_AGENT) == 0) {
            #pragma unroll
            for (int k = 0; k < 16; k++) __builtin_amdgcn_s_sleep(7);
        }
    }
    __syncthreads();                          // publish readiness block-wide

    if (tid < NCLS) off[tid] = kcnt[b * NCLS + tid];
    __syncthreads();
    #pragma unroll
    for (int s = 1; s < NCLS; s <<= 1) {      // Hillis-Steele inclusive scan
        int x = 0;
        if (tid < NCLS && tid >= s) x = off[tid - s];
        __syncthreads();
        if (tid < NCLS) off[tid] += x;
        __syncthreads();
    }
    int cnt = off[NCLS - 1];
    if (cnt > TOPK) cnt = TOPK;
    float f = (off[0] > 0) ? 1.0f : 0.0f;     // person: class-0 kept count > 0

    if (chunk * 64 >= cnt) {                  // pure padding chunk (uniform)
        if (wid == 0) out[(size_t)b * TOPK + i] = 0.0f;
        return;
    }

    // compaction: wave wid copies cells wid, wid+8, ...
    for (int cell = wid; cell < NCLS; cell += RWAVES) {
        int e1 = off[cell];
        int e0 = (cell == 0) ? 0 : off[cell - 1];
        int kc = e1 - e0;
        const float* src = kv + (size_t)(b * NCLS + cell) * CAP;
        for (int j = lane; j < kc; j += 64)
            if (e0 + j < TOPK) v[e0 + j] = src[j];
    }
    __syncthreads();

    float val = (i < cnt) ? v[i] : 0.0f;
    int seg = (cnt + RWAVES - 1) / RWAVES;
    int j0 = wid * seg;
    int j1 = j0 + seg; if (j1 > cnt) j1 = cnt;

    int r = 0, j = j0;
    for (; j < j1 && (j & 3); j++) {
        float t = v[j]; r += (t > val) || (t == val && j < i);
    }
    for (; j + 4 <= j1; j += 4) {             // ds_read_b128 broadcast
        float4 q = *(const float4*)&v[j];
        r += (q.x > val) || (q.x == val && (j + 0) < i);
        r += (q.y > val) || (q.y == val && (j + 1) < i);
        r += (q.z > val) || (q.z == val && (j + 2) < i);
        r += (q.w > val) || (q.w == val && (j + 3) < i);
    }
    for (; j < j1; j++) {
        float t = v[j]; r += (t > val) || (t == val && j < i);
    }
    part[wid][lane] = r;
    __syncthreads();

    if (wid == 0) {
        if (i < cnt) {
            int rank = 0;
            #pragma unroll
            for (int qq = 0; qq < RWAVES; qq++) rank += part[qq][lane];
            out[(size_t)b * TOPK + rank] = val * f;
        } else {
            out[(size_t)b * TOPK + i] = 0.0f;
        }
    }
}

extern "C" void kernel_launch(void* const* d_in, const int* in_sizes, int n_in,
                              void* d_out, int out_size, void* d_ws, size_t ws_size,
                              hipStream_t stream) {
    const float* det = (const float*)d_in[0];
    float* out = (float*)d_out;

    int B = out_size / TOPK;                  // 8
    int N = in_sizes[0] / (B * NCH);          // 10647
    int total = B * N;
    int NT = (N + 1023) / 1024;               // 11
    int NP = NT * 1024;                       // 11264

    // workspace layout (~2.4 MB), 256B-aligned regions
    char* p = (char*)d_ws;
    auto align256 = [](size_t x) { return (x + 255) & ~(size_t)255; };
    size_t o = 0;
    unsigned char* Cc = (unsigned char*)(p + o); o = align256(o + (size_t)B * NP);
    float2* A   = (float2*)(p + o);              o = align256(o + (size_t)B * NP * sizeof(float2));
    float4* REC = (float4*)(p + o);              o = align256(o + (size_t)total * sizeof(float4));
    float*  kv  = (float*)(p + o);               o = align256(o + (size_t)B * NCLS * CAP * sizeof(float));
    int*   kcnt = (int*)(p + o);                 o = align256(o + (size_t)B * NCLS * sizeof(int));
    int*   sync = (int*)(p + o);                 // 16*DSTR ints (arrive|ready)

    int gridA = (total + 3) / 4;              // 4 waves / 256-thr block
    score_kernel<<<gridA, 256, 0, stream>>>(det, A, Cc, REC, sync, N, NP, total);

    void* args[] = { (void*)&A, (void*)&Cc, (void*)&REC, (void*)&kv,
                     (void*)&kcnt, (void*)&sync, (void*)&out,
                     (void*)&N, (void*)&NT, (void*)&NP };
    (void)hipLaunchCooperativeKernel((void*)fused_kernel, dim3(B * KBLK),
                                     dim3(512), args, 0, stream);
}

// Round 17
// 81.381 us; speedup vs baseline: 1.2596x; 1.2596x over previous
//
#include <hip/hip_runtime.h>

// YOLO NMS post-processing, exact reimplementation of the JAX reference.
//  * valid = obj >= 0.8 -> ~2130 valid/image << TOPK=4096: top_k never drops
//    a valid det; invalid dets can neither suppress nor be kept.
//  * suppression requires cls_pred equality -> NMS decomposes into 8x80
//    independent per-(image,class) problems, ~27 boxes each (CAP=96 ~13sig).
//  * R10: per-cell membership via byte-class scan + ballot-compact; NMS fully
//    in wave registers (readlane/ballot, VALU pipe).
//  * Sync scoreboard (fused dur): acquire poll no backoff = 85us (L2-INV
//    storm); relaxed+backoff = 52us (stale per-XCD L2 until evict); RMW+
//    backoff = 63us (coherence-point RMW serialization); acquire+backoff =
//    70us (each acquire invalidates local L2 -> thrash). Work model: B+C
//    ~10-13us, so sync side effects dominate all four.
//  * R17: poll with SYSTEM-scope RELAXED loads (sc read-through: fresh at the
//    coherence point, NO local-cache invalidate, reads parallelize) + ~1us
//    backoff; ready[b] release-stored at SYSTEM scope; every-64-polls agent
//    acquire fallback (progress guarantee); one agent acquire after success
//    for kv/kcnt ordering.

#define NCH    85
#define NCLS   80
#define TOPK   4096
#define CAP    96
#define KBLK   64     // output chunks per image (64 * 64 slots = 4096)
#define RWAVES 8      // j-split waves per rank chunk
#define PBB    80     // phase-B producer blocks (8 cells each = 640 cells)
#define BPI    10     // producer blocks per image
#define DSTR   32     // sync[] stride in ints (128 B / line)

__device__ __forceinline__ float rlf(float v, int l) {
    return __uint_as_float(__builtin_amdgcn_readlane(__float_as_uint(v), l));
}
__device__ __forceinline__ int rli(int v, int l) {
    return __builtin_amdgcn_readlane(v, l);
}

// ---- K1: per-det score/cc (float2), class byte, corner float4; zero sync ---
__global__ void score_kernel(const float* __restrict__ det,
                             float2* __restrict__ A,
                             unsigned char* __restrict__ Cc,
                             float4* __restrict__ REC,
                             int* __restrict__ sync,
                             int N, int NP, int total) {
#pragma clang fp contract(off)   // corner math must match numpy f32 exactly
    if (blockIdx.x == 0)                      // zero ALL sync words
        for (int s = threadIdx.x; s < 16 * DSTR; s += blockDim.x) sync[s] = 0;

    int w    = (blockIdx.x * blockDim.x + threadIdx.x) >> 6;
    int lane = threadIdx.x & 63;
    if (w >= total) return;
    const float* row = det + (size_t)w * NCH;
    int b = w / N, i = w - b * N;

    float obj = row[4];                       // broadcast load
    if (obj < 0.8f) {                         // CONF_THRES, wave-uniform
        if (lane == 0) Cc[(size_t)b * NP + i] = 0xFFu;
        return;
    }
    float va = row[lane];                                    // cols 0..63
    float vb = (lane < NCH - 64) ? row[64 + lane] : -1.0f;   // cols 64..84
    float bestv = -1.0f; int bestc = 1 << 30;
    if (lane >= 5) { bestv = va; bestc = lane - 5; }         // cls 0..58
    if (lane < NCH - 64) {
        int c2 = 59 + lane;                                  // cls 59..79
        if (vb > bestv || (vb == bestv && c2 < bestc)) { bestv = vb; bestc = c2; }
    }
    for (int m = 32; m >= 1; m >>= 1) {
        float ov = __shfl_xor(bestv, m);
        int   oc = __shfl_xor(bestc, m);
        if (ov > bestv || (ov == bestv && oc < bestc)) { bestv = ov; bestc = oc; }
    }
    float x  = rlf(va, 0), y  = rlf(va, 1);
    float bw = rlf(va, 2), bh = rlf(va, 3);
    if (lane == 0) {
        float hw = bw * 0.5f, hh = bh * 0.5f;                // w/2 exact
        A[(size_t)b * NP + i]  = make_float2(obj * bestv, bestv);
        Cc[(size_t)b * NP + i] = (unsigned char)bestc;
        REC[(size_t)w] = make_float4(x - hw, y - hh, x + hw, y + hh);
    }
}

// ---- K2: fused per-cell NMS (80 producer blocks) + rank-scatter (all) ------
// sync layout: arrive[b] at sync[b*DSTR], ready[b] at sync[(8+b)*DSTR].
__global__ void __launch_bounds__(512, 4) fused_kernel(
        const float2* __restrict__ A,
        const unsigned char* __restrict__ Cc,
        const float4* __restrict__ REC,
        float* __restrict__ kv,
        int*   __restrict__ kcnt,
        int*   __restrict__ sync,
        float* __restrict__ out,
        int N, int NT, int NP) {
#pragma clang fp contract(off)   // IoU math must be bit-identical to numpy f32
    const int bid  = blockIdx.x;
    const int tid  = threadIdx.x;
    const int lane = tid & 63;
    const int wid  = tid >> 6;                // 0..7

    __shared__ int   lidx[8][CAP];
    __shared__ int   tmp2[8][CAP];
    __shared__ int   off[NCLS];
    __shared__ float v[TOPK] __attribute__((aligned(16)));
    __shared__ int   part[RWAVES][64];

    // ================= phase B: one wave per (image,class) cell =============
    if (bid < PBB) {
        int cell = bid * 8 + wid;             // 640 cells exactly
        int b = cell / NCLS, c = cell % NCLS;
        unsigned long long mlt = (1ull << lane) - 1ull;

        // membership scan over byte classes (order-free; rank re-sorts)
        const unsigned char* Cb = Cc + (size_t)b * NP;
        int cnt = 0;
        uint4 q = *(const uint4*)(Cb + lane * 16);
        for (int t = 0; t < NT; t++) {
            uint4 qn;
            if (t + 1 < NT) qn = *(const uint4*)(Cb + (size_t)(t + 1) * 1024 + lane * 16);
            int i0 = t * 1024 + lane * 16;
            unsigned xs[4] = { q.x, q.y, q.z, q.w };
            unsigned mm = 0;
            #pragma unroll
            for (int kk = 0; kk < 16; kk++) {
                unsigned byte = (xs[kk >> 2] >> ((kk & 3) * 8)) & 0xFFu;
                if (byte == (unsigned)c && (i0 + kk) < N) mm |= 1u << kk;
            }
            if (__ballot(mm != 0)) {
                #pragma unroll
                for (int kk = 0; kk < 16; kk++) {
                    unsigned long long mk = __ballot((mm >> kk) & 1u);
                    if (mk) {
                        if ((mm >> kk) & 1u) {
                            int p = cnt + __popcll(mk & mlt);
                            if (p < CAP) lidx[wid][p] = i0 + kk;
                        }
                        cnt += __popcll(mk);
                    }
                }
            }
            q = qn;
        }
        int n = cnt < CAP ? cnt : CAP;
        if (n == 0) {
            if (lane == 0) kcnt[cell] = 0;
        } else {
            bool a0 = lane < n, a1 = lane + 64 < n;
            const float2* Ab = A + (size_t)b * NP;
            int id0 = a0 ? lidx[wid][lane]      : 0;
            int id1 = a1 ? lidx[wid][lane + 64] : 0;
            float s0 = a0 ? Ab[id0].x : 0.0f;
            float s1 = a1 ? Ab[id1].x : 0.0f;

            // rank by (score desc, idx asc) == top_k order within class
            int r0 = 0, r1 = 0;
            int m0 = n < 64 ? n : 64;
            for (int j = 0; j < m0; j++) {
                float sj = rlf(s0, j); int ij = rli(id0, j);
                r0 += (sj > s0) || (sj == s0 && ij < id0);
                r1 += (sj > s1) || (sj == s1 && ij < id1);
            }
            for (int j = 64; j < n; j++) {
                float sj = rlf(s1, j - 64); int ij = rli(id1, j - 64);
                r0 += (sj > s0) || (sj == s0 && ij < id0);
                r1 += (sj > s1) || (sj == s1 && ij < id1);
            }
            if (a0) tmp2[wid][r0] = id0;      // same-wave LDS, in-order
            if (a1) tmp2[wid][r1] = id1;
            int di0 = a0 ? tmp2[wid][lane]      : 0;
            int di1 = a1 ? tmp2[wid][lane + 64] : 0;

            // gather sorted records: cc + corners + area (exact ref op order)
            float scc = 0, x10 = 0, y10 = 0, x20 = 0, y20 = 0, ar0 = 0;
            if (a0) {
                scc = Ab[di0].y;
                float4 rc = REC[(size_t)b * N + di0];
                x10 = rc.x; y10 = rc.y; x20 = rc.z; y20 = rc.w;
                ar0 = (x20 - x10 + 1.0f) * (y20 - y10 + 1.0f);
            }
            float tcc = 0, x11 = 0, y11 = 0, x21 = 0, y21 = 0, ar1 = 0;
            if (a1) {
                tcc = Ab[di1].y;
                float4 rc = REC[(size_t)b * N + di1];
                x11 = rc.x; y11 = rc.y; x21 = rc.z; y21 = rc.w;
                ar1 = (x21 - x11 + 1.0f) * (y21 - y11 + 1.0f);
            }

            // column masks: bit i of col(j) = (iou(i,j) > thr), i < j
            unsigned long long col0 = 0, col1a = 0, col1b = 0;
            for (int i = 0; i < n; i++) {
                float ix1, iy1, ix2, iy2, iar;
                if (i < 64) {
                    ix1 = rlf(x10, i); iy1 = rlf(y10, i);
                    ix2 = rlf(x20, i); iy2 = rlf(y20, i); iar = rlf(ar0, i);
                } else {
                    ix1 = rlf(x11, i - 64); iy1 = rlf(y11, i - 64);
                    ix2 = rlf(x21, i - 64); iy2 = rlf(y21, i - 64); iar = rlf(ar1, i - 64);
                }
                if (lane > i && lane < n) {
                    float iw = fminf(ix2, x20) - fmaxf(ix1, x10) + 1.0f;
                    float ih = fminf(iy2, y20) - fmaxf(iy1, y10) + 1.0f;
                    iw = fmaxf(iw, 0.0f); ih = fmaxf(ih, 0.0f);
                    float inter = iw * ih;
                    float iou = inter / (iar + ar0 - inter + 1e-16f);
                    if (iou > 0.4f) col0 |= 1ull << i;        // NMS_THRES
                }
                if (n > 64) {
                    int j2 = lane + 64;
                    if (j2 > i && j2 < n) {
                        float iw = fminf(ix2, x21) - fmaxf(ix1, x11) + 1.0f;
                        float ih = fminf(iy2, y21) - fmaxf(iy1, y11) + 1.0f;
                        iw = fmaxf(iw, 0.0f); ih = fmaxf(ih, 0.0f);
                        float inter = iw * ih;
                        float iou = inter / (iar + ar1 - inter + 1e-16f);
                        if (iou > 0.4f) {
                            if (i < 64) col1a |= 1ull << i;
                            else        col1b |= 1ull << (i - 64);
                        }
                    }
                }
            }

            // greedy: alive rank ii suppresses later columns with its bit set
            bool sup0 = false, sup1 = false;
            for (int ii = 0; ii < n; ii++) {
                bool alive;
                if (ii < 64) alive = !((__ballot(sup0) >> ii) & 1ull);
                else         alive = !((__ballot(sup1) >> (ii - 64)) & 1ull);
                if (alive) {
                    if (ii < 64) {
                        sup0 = sup0 | (((col0  >> ii) & 1ull) != 0);
                        sup1 = sup1 | (((col1a >> ii) & 1ull) != 0);
                    } else {
                        sup1 = sup1 | (((col1b >> (ii - 64)) & 1ull) != 0);
                    }
                }
            }

            // emit kept cc (sorted order) into this cell's private segment
            unsigned long long alive0 = __ballot((!sup0) && a0);
            int kn0 = __popcll(alive0);
            unsigned long long alive1 = (n > 64) ? __ballot((!sup1) && a1) : 0ull;
            int kn = kn0 + __popcll(alive1);
            float* kvc = kv + (size_t)cell * CAP;
            if ((!sup0) && a0) kvc[__popcll(alive0 & mlt)] = scc;
            if ((!sup1) && a1) kvc[kn0 + __popcll(alive1 & mlt)] = tcc;
            if (lane == 0) kcnt[cell] = kn;
        }
        __syncthreads();                      // all 8 cells of block done
        if (tid == 0) {
            int img = bid / BPI;
            int old = __hip_atomic_fetch_add(&sync[img * DSTR], 1,
                                             __ATOMIC_ACQ_REL,
                                             __HIP_MEMORY_SCOPE_AGENT);
            if (old == BPI - 1)               // last producer of this image
                __hip_atomic_store(&sync[(8 + img) * DSTR], 1,
                                   __ATOMIC_RELEASE,
                                   __HIP_MEMORY_SCOPE_SYSTEM);
        }
    }

    // ================= phase C: rank-scatter (all 512 blocks) ===============
    int b     = bid / KBLK;
    int chunk = bid % KBLK;
    int i     = chunk * 64 + lane;

    // R17: poll with SYSTEM-scope RELAXED loads (fresh read-through, no local
    // cache INV, parallel) + ~1us backoff; agent-acquire fallback every 64
    // polls; one agent-acquire after success for kv/kcnt ordering.
    if (tid == 0) {
        int it = 0;
        for (;;) {
            if (__hip_atomic_load(&sync[(8 + b) * DSTR], __ATOMIC_RELAXED,
                                  __HIP_MEMORY_SCOPE_SYSTEM) != 0) break;
            if ((++it & 63) == 0 &&
                __hip_atomic_load(&sync[(8 + b) * DSTR], __ATOMIC_ACQUIRE,
                                  __HIP_MEMORY_SCOPE_AGENT) != 0) break;
            #pragma unroll
            for (int k = 0; k < 4; k++) __builtin_amdgcn_s_sleep(7);
        }
        (void)__hip_atomic_load(&sync[(8 + b) * DSTR], __ATOMIC_ACQUIRE,
                                __HIP_MEMORY_SCOPE_AGENT);
    }
    __syncthreads();                          // publish readiness block-wide

    if (tid < NCLS) off[tid] = kcnt[b * NCLS + tid];
    __syncthreads();
    #pragma unroll
    for (int s = 1; s < NCLS; s <<= 1) {      // Hillis-Steele inclusive scan
        int x = 0;
        if (tid < NCLS && tid >= s) x = off[tid - s];
        __syncthreads();
        if (tid < NCLS) off[tid] += x;
        __syncthreads();
    }
    int cnt = off[NCLS - 1];
    if (cnt > TOPK) cnt = TOPK;
    float f = (off[0] > 0) ? 1.0f : 0.0f;     // person: class-0 kept count > 0

    if (chunk * 64 >= cnt) {                  // pure padding chunk (uniform)
        if (wid == 0) out[(size_t)b * TOPK + i] = 0.0f;
        return;
    }

    // compaction: wave wid copies cells wid, wid+8, ...
    for (int cell = wid; cell < NCLS; cell += RWAVES) {
        int e1 = off[cell];
        int e0 = (cell == 0) ? 0 : off[cell - 1];
        int kc = e1 - e0;
        const float* src = kv + (size_t)(b * NCLS + cell) * CAP;
        for (int j = lane; j < kc; j += 64)
            if (e0 + j < TOPK) v[e0 + j] = src[j];
    }
    __syncthreads();

    float val = (i < cnt) ? v[i] : 0.0f;
    int seg = (cnt + RWAVES - 1) / RWAVES;
    int j0 = wid * seg;
    int j1 = j0 + seg; if (j1 > cnt) j1 = cnt;

    int r = 0, j = j0;
    for (; j < j1 && (j & 3); j++) {
        float t = v[j]; r += (t > val) || (t == val && j < i);
    }
    for (; j + 4 <= j1; j += 4) {             // ds_read_b128 broadcast
        float4 q = *(const float4*)&v[j];
        r += (q.x > val) || (q.x == val && (j + 0) < i);
        r += (q.y > val) || (q.y == val && (j + 1) < i);
        r += (q.z > val) || (q.z == val && (j + 2) < i);
        r += (q.w > val) || (q.w == val && (j + 3) < i);
    }
    for (; j < j1; j++) {
        float t = v[j]; r += (t > val) || (t == val && j < i);
    }
    part[wid][lane] = r;
    __syncthreads();

    if (wid == 0) {
        if (i < cnt) {
            int rank = 0;
            #pragma unroll
            for (int qq = 0; qq < RWAVES; qq++) rank += part[qq][lane];
            out[(size_t)b * TOPK + rank] = val * f;
        } else {
            out[(size_t)b * TOPK + i] = 0.0f;
        }
    }
}

extern "C" void kernel_launch(void* const* d_in, const int* in_sizes, int n_in,
                              void* d_out, int out_size, void* d_ws, size_t ws_size,
                              hipStream_t stream) {
    const float* det = (const float*)d_in[0];
    float* out = (float*)d_out;

    int B = out_size / TOPK;                  // 8
    int N = in_sizes[0] / (B * NCH);          // 10647
    int total = B * N;
    int NT = (N + 1023) / 1024;               // 11
    int NP = NT * 1024;                       // 11264

    // workspace layout (~2.4 MB), 256B-aligned regions
    char* p = (char*)d_ws;
    auto align256 = [](size_t x) { return (x + 255) & ~(size_t)255; };
    size_t o = 0;
    unsigned char* Cc = (unsigned char*)(p + o); o = align256(o + (size_t)B * NP);
    float2* A   = (float2*)(p + o);              o = align256(o + (size_t)B * NP * sizeof(float2));
    float4* REC = (float4*)(p + o);              o = align256(o + (size_t)total * sizeof(float4));
    float*  kv  = (float*)(p + o);               o = align256(o + (size_t)B * NCLS * CAP * sizeof(float));
    int*   kcnt = (int*)(p + o);                 o = align256(o + (size_t)B * NCLS * sizeof(int));
    int*   sync = (int*)(p + o);                 // 16*DSTR ints (arrive|ready)

    int gridA = (total + 3) / 4;              // 4 waves / 256-thr block
    score_kernel<<<gridA, 256, 0, stream>>>(det, A, Cc, REC, sync, N, NP, total);

    void* args[] = { (void*)&A, (void*)&Cc, (void*)&REC, (void*)&kv,
                     (void*)&kcnt, (void*)&sync, (void*)&out,
                     (void*)&N, (void*)&NT, (void*)&NP };
    (void)hipLaunchCooperativeKernel((void*)fused_kernel, dim3(B * KBLK),
                                     dim3(512), args, 0, stream);
}

// Round 18
// 62.037 us; speedup vs baseline: 1.6524x; 1.3118x over previous
//
#include <hip/hip_runtime.h>

// YOLO NMS post-processing, exact reimplementation of the JAX reference.
//  * valid = obj >= 0.8 -> ~2130 valid/image << TOPK=4096: top_k never drops
//    a valid det; invalid dets can neither suppress nor be kept.
//  * suppression requires cls_pred equality -> NMS decomposes into 8x80
//    independent per-(image,class) problems, ~27 boxes each (CAP=96 ~13sig).
//  * R10: per-cell membership via byte-class scan + ballot-compact; NMS fully
//    in wave registers (readlane/ballot, VALU pipe). Total 62.3us = best.
//  * R11-R17 (fused NMS+rank, 5 sync mechanisms): fused kernel never below
//    49.5us vs ~10us of work -> intra-kernel cross-XCD handoff is WORSE than
//    a kernel boundary (~13-16us/node measured by subtraction, 3 independent
//    estimates agree). Conclusion: plain 3-node pipeline is the right shape.
//  * R18: revert to R10 + micro-opts: A written only for valid dets (invalid
//    never read via A; -550KB scattered stores), no sync words at all.

#define NCH    85
#define NCLS   80
#define TOPK   4096
#define CAP    96
#define KBLK   64     // output chunks per image (64 * 64 slots = 4096)
#define RWAVES 8      // j-split waves per rank chunk

__device__ __forceinline__ float rlf(float v, int l) {
    return __uint_as_float(__builtin_amdgcn_readlane(__float_as_uint(v), l));
}
__device__ __forceinline__ int rli(int v, int l) {
    return __builtin_amdgcn_readlane(v, l);
}

// ---- K1: per-det score/cc (float2, valid only), class byte, corner float4 --
__global__ void score_kernel(const float* __restrict__ det,
                             float2* __restrict__ A,
                             unsigned char* __restrict__ Cc,
                             float4* __restrict__ REC,
                             int N, int NP, int total) {
#pragma clang fp contract(off)   // corner math must match numpy f32 exactly
    int w    = (blockIdx.x * blockDim.x + threadIdx.x) >> 6;
    int lane = threadIdx.x & 63;
    if (w >= total) return;
    const float* row = det + (size_t)w * NCH;
    int b = w / N, i = w - b * N;

    float obj = row[4];                       // broadcast load
    if (obj < 0.8f) {                         // CONF_THRES, wave-uniform
        if (lane == 0) Cc[(size_t)b * NP + i] = 0xFFu;
        return;
    }
    float va = row[lane];                                    // cols 0..63
    float vb = (lane < NCH - 64) ? row[64 + lane] : -1.0f;   // cols 64..84
    float bestv = -1.0f; int bestc = 1 << 30;
    if (lane >= 5) { bestv = va; bestc = lane - 5; }         // cls 0..58
    if (lane < NCH - 64) {
        int c2 = 59 + lane;                                  // cls 59..79
        if (vb > bestv || (vb == bestv && c2 < bestc)) { bestv = vb; bestc = c2; }
    }
    for (int m = 32; m >= 1; m >>= 1) {
        float ov = __shfl_xor(bestv, m);
        int   oc = __shfl_xor(bestc, m);
        if (ov > bestv || (ov == bestv && oc < bestc)) { bestv = ov; bestc = oc; }
    }
    float x  = rlf(va, 0), y  = rlf(va, 1);
    float bw = rlf(va, 2), bh = rlf(va, 3);
    if (lane == 0) {
        float hw = bw * 0.5f, hh = bh * 0.5f;                // w/2 exact
        A[(size_t)b * NP + i]  = make_float2(obj * bestv, bestv);
        Cc[(size_t)b * NP + i] = (unsigned char)bestc;
        REC[(size_t)w] = make_float4(x - hw, y - hh, x + hw, y + hh);
    }
}

// ---- K2: one wave per (image,class): scan bytes, rank, IoU, greedy ---------
__global__ void __launch_bounds__(64) nms_kernel(
        const float2* __restrict__ A,
        const unsigned char* __restrict__ Cc,
        const float4* __restrict__ REC,
        float* __restrict__ kv,
        int*   __restrict__ kcnt,
        int N, int NT, int NP) {
#pragma clang fp contract(off)   // IoU math must be bit-identical to numpy f32
    int cell = blockIdx.x;
    int b = cell / NCLS, c = cell % NCLS;
    int lane = threadIdx.x;
    unsigned long long mlt = (1ull << lane) - 1ull;

    __shared__ int lidx[CAP];
    __shared__ int tmpidx[CAP];

    // --- membership scan over byte classes (order-free append) ---
    const unsigned char* Cb = Cc + (size_t)b * NP;
    int cnt = 0;
    uint4 q = *(const uint4*)(Cb + lane * 16);          // prefetch t=0
    for (int t = 0; t < NT; t++) {
        uint4 qn;
        if (t + 1 < NT) qn = *(const uint4*)(Cb + (size_t)(t + 1) * 1024 + lane * 16);
        int i0 = t * 1024 + lane * 16;
        unsigned xs[4] = { q.x, q.y, q.z, q.w };
        unsigned mm = 0;
        #pragma unroll
        for (int kk = 0; kk < 16; kk++) {
            unsigned byte = (xs[kk >> 2] >> ((kk & 3) * 8)) & 0xFFu;
            if (byte == (unsigned)c && (i0 + kk) < N) mm |= 1u << kk;
        }
        if (__ballot(mm != 0)) {
            #pragma unroll
            for (int kk = 0; kk < 16; kk++) {
                unsigned long long mk = __ballot((mm >> kk) & 1u);
                if (mk) {
                    if ((mm >> kk) & 1u) {
                        int p = cnt + __popcll(mk & mlt);
                        if (p < CAP) lidx[p] = i0 + kk;
                    }
                    cnt += __popcll(mk);
                }
            }
        }
        q = qn;
    }
    int n = cnt < CAP ? cnt : CAP;
    if (n == 0) { if (lane == 0) kcnt[cell] = 0; return; }

    bool a0 = lane < n, a1 = lane + 64 < n;
    const float2* Ab = A + (size_t)b * NP;
    int id0 = a0 ? lidx[lane]      : 0;
    int id1 = a1 ? lidx[lane + 64] : 0;
    float s0 = a0 ? Ab[id0].x : 0.0f;
    float s1 = a1 ? Ab[id1].x : 0.0f;

    // --- rank by (score desc, idx asc) == top_k order within class ---
    int r0 = 0, r1 = 0;
    int m0 = n < 64 ? n : 64;
    for (int j = 0; j < m0; j++) {
        float sj = rlf(s0, j); int ij = rli(id0, j);
        r0 += (sj > s0) || (sj == s0 && ij < id0);
        r1 += (sj > s1) || (sj == s1 && ij < id1);
    }
    for (int j = 64; j < n; j++) {
        float sj = rlf(s1, j - 64); int ij = rli(id1, j - 64);
        r0 += (sj > s0) || (sj == s0 && ij < id0);
        r1 += (sj > s1) || (sj == s1 && ij < id1);
    }
    if (a0) tmpidx[r0] = id0;      // same-wave LDS, program-order safe
    if (a1) tmpidx[r1] = id1;
    int di0 = a0 ? tmpidx[lane]      : 0;
    int di1 = a1 ? tmpidx[lane + 64] : 0;

    // --- gather sorted records: cc + corners + area (exact ref op order) ---
    float scc = 0, x10 = 0, y10 = 0, x20 = 0, y20 = 0, ar0 = 0;
    if (a0) {
        scc = Ab[di0].y;
        float4 rc = REC[(size_t)b * N + di0];
        x10 = rc.x; y10 = rc.y; x20 = rc.z; y20 = rc.w;
        ar0 = (x20 - x10 + 1.0f) * (y20 - y10 + 1.0f);
    }
    float tcc = 0, x11 = 0, y11 = 0, x21 = 0, y21 = 0, ar1 = 0;
    if (a1) {
        tcc = Ab[di1].y;
        float4 rc = REC[(size_t)b * N + di1];
        x11 = rc.x; y11 = rc.y; x21 = rc.z; y21 = rc.w;
        ar1 = (x21 - x11 + 1.0f) * (y21 - y11 + 1.0f);
    }

    // --- column masks: bit i of col(j) = (iou(i,j) > thr), i < j ---
    unsigned long long col0 = 0, col1a = 0, col1b = 0;
    for (int i = 0; i < n; i++) {
        float ix1, iy1, ix2, iy2, iar;
        if (i < 64) {
            ix1 = rlf(x10, i); iy1 = rlf(y10, i);
            ix2 = rlf(x20, i); iy2 = rlf(y20, i); iar = rlf(ar0, i);
        } else {
            ix1 = rlf(x11, i - 64); iy1 = rlf(y11, i - 64);
            ix2 = rlf(x21, i - 64); iy2 = rlf(y21, i - 64); iar = rlf(ar1, i - 64);
        }
        if (lane > i && lane < n) {
            float iw = fminf(ix2, x20) - fmaxf(ix1, x10) + 1.0f;
            float ih = fminf(iy2, y20) - fmaxf(iy1, y10) + 1.0f;
            iw = fmaxf(iw, 0.0f); ih = fmaxf(ih, 0.0f);
            float inter = iw * ih;
            float iou = inter / (iar + ar0 - inter + 1e-16f);
            if (iou > 0.4f) col0 |= 1ull << i;                // NMS_THRES
        }
        if (n > 64) {
            int j2 = lane + 64;
            if (j2 > i && j2 < n) {
                float iw = fminf(ix2, x21) - fmaxf(ix1, x11) + 1.0f;
                float ih = fminf(iy2, y21) - fmaxf(iy1, y11) + 1.0f;
                iw = fmaxf(iw, 0.0f); ih = fmaxf(ih, 0.0f);
                float inter = iw * ih;
                float iou = inter / (iar + ar1 - inter + 1e-16f);
                if (iou > 0.4f) {
                    if (i < 64) col1a |= 1ull << i;
                    else        col1b |= 1ull << (i - 64);
                }
            }
        }
    }

    // --- greedy: alive rank ii suppresses later columns with its bit set ---
    bool sup0 = false, sup1 = false;
    for (int ii = 0; ii < n; ii++) {
        bool alive;
        if (ii < 64) alive = !((__ballot(sup0) >> ii) & 1ull);
        else         alive = !((__ballot(sup1) >> (ii - 64)) & 1ull);
        if (alive) {
            if (ii < 64) {
                sup0 = sup0 | (((col0  >> ii) & 1ull) != 0);
                sup1 = sup1 | (((col1a >> ii) & 1ull) != 0);
            } else {
                sup1 = sup1 | (((col1b >> (ii - 64)) & 1ull) != 0);
            }
        }
    }

    // --- emit kept cc (sorted order) into this cell's private segment ---
    unsigned long long alive0 = __ballot((!sup0) && a0);
    int kn0 = __popcll(alive0);
    unsigned long long alive1 = (n > 64) ? __ballot((!sup1) && a1) : 0ull;
    int kn = kn0 + __popcll(alive1);
    float* kvc = kv + (size_t)cell * CAP;
    if ((!sup0) && a0) kvc[__popcll(alive0 & mlt)] = scc;
    if ((!sup1) && a1) kvc[kn0 + __popcll(alive1 & mlt)] = tcc;
    if (lane == 0) kcnt[cell] = kn;
}

// ---- K3: prefix-scan 80 cell counts, compact, rank-scatter ------------------
__global__ void __launch_bounds__(512) rank_out_kernel(
        const float* __restrict__ kv,
        const int*   __restrict__ kcnt,
        float* __restrict__ out) {
    int b     = blockIdx.x / KBLK;
    int chunk = blockIdx.x % KBLK;
    int tid   = threadIdx.x;                  // 0..511
    int lane  = tid & 63;
    int wid   = tid >> 6;                     // 0..7
    int i     = chunk * 64 + lane;

    __shared__ int   off[NCLS];
    __shared__ float v[TOPK] __attribute__((aligned(16)));
    __shared__ int   part[RWAVES][64];

    if (tid < NCLS) off[tid] = kcnt[b * NCLS + tid];
    __syncthreads();
    #pragma unroll
    for (int s = 1; s < NCLS; s <<= 1) {      // Hillis-Steele inclusive scan
        int x = 0;
        if (tid < NCLS && tid >= s) x = off[tid - s];
        __syncthreads();
        if (tid < NCLS) off[tid] += x;
        __syncthreads();
    }
    int cnt = off[NCLS - 1];
    if (cnt > TOPK) cnt = TOPK;
    float f = (off[0] > 0) ? 1.0f : 0.0f;     // person: class-0 kept count > 0

    if (chunk * 64 >= cnt) {                  // pure padding chunk
        if (wid == 0) out[(size_t)b * TOPK + i] = 0.0f;
        return;
    }

    // compaction: wave wid copies cells wid, wid+8, ...
    for (int cell = wid; cell < NCLS; cell += RWAVES) {
        int e1 = off[cell];
        int e0 = (cell == 0) ? 0 : off[cell - 1];
        int kc = e1 - e0;
        const float* src = kv + (size_t)(b * NCLS + cell) * CAP;
        for (int j = lane; j < kc; j += 64)
            if (e0 + j < TOPK) v[e0 + j] = src[j];
    }
    __syncthreads();

    float val = (i < cnt) ? v[i] : 0.0f;
    int seg = (cnt + RWAVES - 1) / RWAVES;
    int j0 = wid * seg;
    int j1 = j0 + seg; if (j1 > cnt) j1 = cnt;

    int r = 0, j = j0;
    for (; j < j1 && (j & 3); j++) {
        float t = v[j]; r += (t > val) || (t == val && j < i);
    }
    for (; j + 4 <= j1; j += 4) {             // ds_read_b128 broadcast
        float4 q = *(const float4*)&v[j];
        r += (q.x > val) || (q.x == val && (j + 0) < i);
        r += (q.y > val) || (q.y == val && (j + 1) < i);
        r += (q.z > val) || (q.z == val && (j + 2) < i);
        r += (q.w > val) || (q.w == val && (j + 3) < i);
    }
    for (; j < j1; j++) {
        float t = v[j]; r += (t > val) || (t == val && j < i);
    }
    part[wid][lane] = r;
    __syncthreads();

    if (wid == 0) {
        if (i < cnt) {
            int rank = 0;
            #pragma unroll
            for (int qq = 0; qq < RWAVES; qq++) rank += part[qq][lane];
            out[(size_t)b * TOPK + rank] = val * f;
        } else {
            out[(size_t)b * TOPK + i] = 0.0f;
        }
    }
}

extern "C" void kernel_launch(void* const* d_in, const int* in_sizes, int n_in,
                              void* d_out, int out_size, void* d_ws, size_t ws_size,
                              hipStream_t stream) {
    const float* det = (const float*)d_in[0];
    float* out = (float*)d_out;

    int B = out_size / TOPK;                  // 8
    int N = in_sizes[0] / (B * NCH);          // 10647
    int total = B * N;
    int NT = (N + 1023) / 1024;               // 11
    int NP = NT * 1024;                       // 11264

    // workspace layout (~2.4 MB), 256B-aligned regions, nothing pre-zeroed
    char* p = (char*)d_ws;
    auto align256 = [](size_t x) { return (x + 255) & ~(size_t)255; };
    size_t o = 0;
    unsigned char* Cc = (unsigned char*)(p + o); o = align256(o + (size_t)B * NP);
    float2* A   = (float2*)(p + o);              o = align256(o + (size_t)B * NP * sizeof(float2));
    float4* REC = (float4*)(p + o);              o = align256(o + (size_t)total * sizeof(float4));
    float*  kv  = (float*)(p + o);               o = align256(o + (size_t)B * NCLS * CAP * sizeof(float));
    int*   kcnt = (int*)(p + o);

    int gridA = (total + 3) / 4;              // 4 waves / 256-thr block
    score_kernel<<<gridA, 256, 0, stream>>>(det, A, Cc, REC, N, NP, total);
    nms_kernel<<<B * NCLS, 64, 0, stream>>>(A, Cc, REC, kv, kcnt, N, NT, NP);
    rank_out_kernel<<<B * KBLK, 512, 0, stream>>>(kv, kcnt, out);
}

// Round 19
// 60.647 us; speedup vs baseline: 1.6903x; 1.0229x over previous
//
#include <hip/hip_runtime.h>

// YOLO NMS post-processing, exact reimplementation of the JAX reference.
//  * valid = obj >= 0.8 -> ~2130 valid/image << TOPK=4096: top_k never drops
//    a valid det; invalid dets can neither suppress nor be kept.
//  * suppression requires cls_pred equality -> NMS decomposes into 8x80
//    independent per-(image,class) problems, ~27 boxes each (CAP=96 ~13sig).
//  * Structure (locked after R1-R18): 3 nodes = full-chip score pass ->
//    per-cell ballot NMS -> full-chip rank-scatter. Ledger: graph fixed cost
//    ~15us + ~12-15us/extra node; kernels ~14-16us total. All node-merging
//    options priced out: per-image concentration 44us/CU, redundant NMS 29us,
//    intra-kernel cross-XCD handoff >=35us over 5 sync mechanisms (R11-R17).
//  * R19: K3's 26-barrier Hillis-Steele scan -> single-wave shfl_up scan
//    (1 barrier). Last work-side shave; everything else byte-identical.

#define NCH    85
#define NCLS   80
#define TOPK   4096
#define CAP    96
#define KBLK   64     // output chunks per image (64 * 64 slots = 4096)
#define RWAVES 8      // j-split waves per rank chunk

__device__ __forceinline__ float rlf(float v, int l) {
    return __uint_as_float(__builtin_amdgcn_readlane(__float_as_uint(v), l));
}
__device__ __forceinline__ int rli(int v, int l) {
    return __builtin_amdgcn_readlane(v, l);
}

// ---- K1: per-det score/cc (float2, valid only), class byte, corner float4 --
__global__ void score_kernel(const float* __restrict__ det,
                             float2* __restrict__ A,
                             unsigned char* __restrict__ Cc,
                             float4* __restrict__ REC,
                             int N, int NP, int total) {
#pragma clang fp contract(off)   // corner math must match numpy f32 exactly
    int w    = (blockIdx.x * blockDim.x + threadIdx.x) >> 6;
    int lane = threadIdx.x & 63;
    if (w >= total) return;
    const float* row = det + (size_t)w * NCH;
    int b = w / N, i = w - b * N;

    float obj = row[4];                       // broadcast load
    if (obj < 0.8f) {                         // CONF_THRES, wave-uniform
        if (lane == 0) Cc[(size_t)b * NP + i] = 0xFFu;
        return;
    }
    float va = row[lane];                                    // cols 0..63
    float vb = (lane < NCH - 64) ? row[64 + lane] : -1.0f;   // cols 64..84
    float bestv = -1.0f; int bestc = 1 << 30;
    if (lane >= 5) { bestv = va; bestc = lane - 5; }         // cls 0..58
    if (lane < NCH - 64) {
        int c2 = 59 + lane;                                  // cls 59..79
        if (vb > bestv || (vb == bestv && c2 < bestc)) { bestv = vb; bestc = c2; }
    }
    for (int m = 32; m >= 1; m >>= 1) {
        float ov = __shfl_xor(bestv, m);
        int   oc = __shfl_xor(bestc, m);
        if (ov > bestv || (ov == bestv && oc < bestc)) { bestv = ov; bestc = oc; }
    }
    float x  = rlf(va, 0), y  = rlf(va, 1);
    float bw = rlf(va, 2), bh = rlf(va, 3);
    if (lane == 0) {
        float hw = bw * 0.5f, hh = bh * 0.5f;                // w/2 exact
        A[(size_t)b * NP + i]  = make_float2(obj * bestv, bestv);
        Cc[(size_t)b * NP + i] = (unsigned char)bestc;
        REC[(size_t)w] = make_float4(x - hw, y - hh, x + hw, y + hh);
    }
}

// ---- K2: one wave per (image,class): scan bytes, rank, IoU, greedy ---------
__global__ void __launch_bounds__(64) nms_kernel(
        const float2* __restrict__ A,
        const unsigned char* __restrict__ Cc,
        const float4* __restrict__ REC,
        float* __restrict__ kv,
        int*   __restrict__ kcnt,
        int N, int NT, int NP) {
#pragma clang fp contract(off)   // IoU math must be bit-identical to numpy f32
    int cell = blockIdx.x;
    int b = cell / NCLS, c = cell % NCLS;
    int lane = threadIdx.x;
    unsigned long long mlt = (1ull << lane) - 1ull;

    __shared__ int lidx[CAP];
    __shared__ int tmpidx[CAP];

    // --- membership scan over byte classes (order-free append) ---
    const unsigned char* Cb = Cc + (size_t)b * NP;
    int cnt = 0;
    uint4 q = *(const uint4*)(Cb + lane * 16);          // prefetch t=0
    for (int t = 0; t < NT; t++) {
        uint4 qn;
        if (t + 1 < NT) qn = *(const uint4*)(Cb + (size_t)(t + 1) * 1024 + lane * 16);
        int i0 = t * 1024 + lane * 16;
        unsigned xs[4] = { q.x, q.y, q.z, q.w };
        unsigned mm = 0;
        #pragma unroll
        for (int kk = 0; kk < 16; kk++) {
            unsigned byte = (xs[kk >> 2] >> ((kk & 3) * 8)) & 0xFFu;
            if (byte == (unsigned)c && (i0 + kk) < N) mm |= 1u << kk;
        }
        if (__ballot(mm != 0)) {
            #pragma unroll
            for (int kk = 0; kk < 16; kk++) {
                unsigned long long mk = __ballot((mm >> kk) & 1u);
                if (mk) {
                    if ((mm >> kk) & 1u) {
                        int p = cnt + __popcll(mk & mlt);
                        if (p < CAP) lidx[p] = i0 + kk;
                    }
                    cnt += __popcll(mk);
                }
            }
        }
        q = qn;
    }
    int n = cnt < CAP ? cnt : CAP;
    if (n == 0) { if (lane == 0) kcnt[cell] = 0; return; }

    bool a0 = lane < n, a1 = lane + 64 < n;
    const float2* Ab = A + (size_t)b * NP;
    int id0 = a0 ? lidx[lane]      : 0;
    int id1 = a1 ? lidx[lane + 64] : 0;
    float s0 = a0 ? Ab[id0].x : 0.0f;
    float s1 = a1 ? Ab[id1].x : 0.0f;

    // --- rank by (score desc, idx asc) == top_k order within class ---
    int r0 = 0, r1 = 0;
    int m0 = n < 64 ? n : 64;
    for (int j = 0; j < m0; j++) {
        float sj = rlf(s0, j); int ij = rli(id0, j);
        r0 += (sj > s0) || (sj == s0 && ij < id0);
        r1 += (sj > s1) || (sj == s1 && ij < id1);
    }
    for (int j = 64; j < n; j++) {
        float sj = rlf(s1, j - 64); int ij = rli(id1, j - 64);
        r0 += (sj > s0) || (sj == s0 && ij < id0);
        r1 += (sj > s1) || (sj == s1 && ij < id1);
    }
    if (a0) tmpidx[r0] = id0;      // same-wave LDS, program-order safe
    if (a1) tmpidx[r1] = id1;
    int di0 = a0 ? tmpidx[lane]      : 0;
    int di1 = a1 ? tmpidx[lane + 64] : 0;

    // --- gather sorted records: cc + corners + area (exact ref op order) ---
    float scc = 0, x10 = 0, y10 = 0, x20 = 0, y20 = 0, ar0 = 0;
    if (a0) {
        scc = Ab[di0].y;
        float4 rc = REC[(size_t)b * N + di0];
        x10 = rc.x; y10 = rc.y; x20 = rc.z; y20 = rc.w;
        ar0 = (x20 - x10 + 1.0f) * (y20 - y10 + 1.0f);
    }
    float tcc = 0, x11 = 0, y11 = 0, x21 = 0, y21 = 0, ar1 = 0;
    if (a1) {
        tcc = Ab[di1].y;
        float4 rc = REC[(size_t)b * N + di1];
        x11 = rc.x; y11 = rc.y; x21 = rc.z; y21 = rc.w;
        ar1 = (x21 - x11 + 1.0f) * (y21 - y11 + 1.0f);
    }

    // --- column masks: bit i of col(j) = (iou(i,j) > thr), i < j ---
    unsigned long long col0 = 0, col1a = 0, col1b = 0;
    for (int i = 0; i < n; i++) {
        float ix1, iy1, ix2, iy2, iar;
        if (i < 64) {
            ix1 = rlf(x10, i); iy1 = rlf(y10, i);
            ix2 = rlf(x20, i); iy2 = rlf(y20, i); iar = rlf(ar0, i);
        } else {
            ix1 = rlf(x11, i - 64); iy1 = rlf(y11, i - 64);
            ix2 = rlf(x21, i - 64); iy2 = rlf(y21, i - 64); iar = rlf(ar1, i - 64);
        }
        if (lane > i && lane < n) {
            float iw = fminf(ix2, x20) - fmaxf(ix1, x10) + 1.0f;
            float ih = fminf(iy2, y20) - fmaxf(iy1, y10) + 1.0f;
            iw = fmaxf(iw, 0.0f); ih = fmaxf(ih, 0.0f);
            float inter = iw * ih;
            float iou = inter / (iar + ar0 - inter + 1e-16f);
            if (iou > 0.4f) col0 |= 1ull << i;                // NMS_THRES
        }
        if (n > 64) {
            int j2 = lane + 64;
            if (j2 > i && j2 < n) {
                float iw = fminf(ix2, x21) - fmaxf(ix1, x11) + 1.0f;
                float ih = fminf(iy2, y21) - fmaxf(iy1, y11) + 1.0f;
                iw = fmaxf(iw, 0.0f); ih = fmaxf(ih, 0.0f);
                float inter = iw * ih;
                float iou = inter / (iar + ar1 - inter + 1e-16f);
                if (iou > 0.4f) {
                    if (i < 64) col1a |= 1ull << i;
                    else        col1b |= 1ull << (i - 64);
                }
            }
        }
    }

    // --- greedy: alive rank ii suppresses later columns with its bit set ---
    bool sup0 = false, sup1 = false;
    for (int ii = 0; ii < n; ii++) {
        bool alive;
        if (ii < 64) alive = !((__ballot(sup0) >> ii) & 1ull);
        else         alive = !((__ballot(sup1) >> (ii - 64)) & 1ull);
        if (alive) {
            if (ii < 64) {
                sup0 = sup0 | (((col0  >> ii) & 1ull) != 0);
                sup1 = sup1 | (((col1a >> ii) & 1ull) != 0);
            } else {
                sup1 = sup1 | (((col1b >> (ii - 64)) & 1ull) != 0);
            }
        }
    }

    // --- emit kept cc (sorted order) into this cell's private segment ---
    unsigned long long alive0 = __ballot((!sup0) && a0);
    int kn0 = __popcll(alive0);
    unsigned long long alive1 = (n > 64) ? __ballot((!sup1) && a1) : 0ull;
    int kn = kn0 + __popcll(alive1);
    float* kvc = kv + (size_t)cell * CAP;
    if ((!sup0) && a0) kvc[__popcll(alive0 & mlt)] = scc;
    if ((!sup1) && a1) kvc[kn0 + __popcll(alive1 & mlt)] = tcc;
    if (lane == 0) kcnt[cell] = kn;
}

// ---- K3: wave-scan 80 cell counts, compact, rank-scatter --------------------
__global__ void __launch_bounds__(512) rank_out_kernel(
        const float* __restrict__ kv,
        const int*   __restrict__ kcnt,
        float* __restrict__ out) {
    int b     = blockIdx.x / KBLK;
    int chunk = blockIdx.x % KBLK;
    int tid   = threadIdx.x;                  // 0..511
    int lane  = tid & 63;
    int wid   = tid >> 6;                     // 0..7
    int i     = chunk * 64 + lane;

    __shared__ int   off[NCLS];
    __shared__ float v[TOPK] __attribute__((aligned(16)));
    __shared__ int   part[RWAVES][64];

    // R19: single-wave inclusive scan of the 80 counts (1 barrier, was 26)
    if (wid == 0) {
        int x0 = (lane < NCLS)      ? kcnt[b * NCLS + lane]      : 0;
        int x1 = (lane < NCLS - 64) ? kcnt[b * NCLS + 64 + lane] : 0;
        #pragma unroll
        for (int d = 1; d < 64; d <<= 1) {
            int y = __shfl_up(x0, d);
            if (lane >= d) x0 += y;
        }
        int tot0 = __shfl(x0, 63);
        #pragma unroll
        for (int d = 1; d < 16; d <<= 1) {
            int y = __shfl_up(x1, d);
            if (lane >= d) x1 += y;
        }
        if (lane < NCLS)      off[lane]      = x0;
        if (lane < NCLS - 64) off[64 + lane] = x1 + tot0;
    }
    __syncthreads();

    int cnt = off[NCLS - 1];
    if (cnt > TOPK) cnt = TOPK;
    float f = (off[0] > 0) ? 1.0f : 0.0f;     // person: class-0 kept count > 0

    if (chunk * 64 >= cnt) {                  // pure padding chunk
        if (wid == 0) out[(size_t)b * TOPK + i] = 0.0f;
        return;
    }

    // compaction: wave wid copies cells wid, wid+8, ...
    for (int cell = wid; cell < NCLS; cell += RWAVES) {
        int e1 = off[cell];
        int e0 = (cell == 0) ? 0 : off[cell - 1];
        int kc = e1 - e0;
        const float* src = kv + (size_t)(b * NCLS + cell) * CAP;
        for (int j = lane; j < kc; j += 64)
            if (e0 + j < TOPK) v[e0 + j] = src[j];
    }
    __syncthreads();

    float val = (i < cnt) ? v[i] : 0.0f;
    int seg = (cnt + RWAVES - 1) / RWAVES;
    int j0 = wid * seg;
    int j1 = j0 + seg; if (j1 > cnt) j1 = cnt;

    int r = 0, j = j0;
    for (; j < j1 && (j & 3); j++) {
        float t = v[j]; r += (t > val) || (t == val && j < i);
    }
    for (; j + 4 <= j1; j += 4) {             // ds_read_b128 broadcast
        float4 q = *(const float4*)&v[j];
        r += (q.x > val) || (q.x == val && (j + 0) < i);
        r += (q.y > val) || (q.y == val && (j + 1) < i);
        r += (q.z > val) || (q.z == val && (j + 2) < i);
        r += (q.w > val) || (q.w == val && (j + 3) < i);
    }
    for (; j < j1; j++) {
        float t = v[j]; r += (t > val) || (t == val && j < i);
    }
    part[wid][lane] = r;
    __syncthreads();

    if (wid == 0) {
        if (i < cnt) {
            int rank = 0;
            #pragma unroll
            for (int qq = 0; qq < RWAVES; qq++) rank += part[qq][lane];
            out[(size_t)b * TOPK + rank] = val * f;
        } else {
            out[(size_t)b * TOPK + i] = 0.0f;
        }
    }
}

extern "C" void kernel_launch(void* const* d_in, const int* in_sizes, int n_in,
                              void* d_out, int out_size, void* d_ws, size_t ws_size,
                              hipStream_t stream) {
    const float* det = (const float*)d_in[0];
    float* out = (float*)d_out;

    int B = out_size / TOPK;                  // 8
    int N = in_sizes[0] / (B * NCH);          // 10647
    int total = B * N;
    int NT = (N + 1023) / 1024;               // 11
    int NP = NT * 1024;                       // 11264

    // workspace layout (~2.4 MB), 256B-aligned regions, nothing pre-zeroed
    char* p = (char*)d_ws;
    auto align256 = [](size_t x) { return (x + 255) & ~(size_t)255; };
    size_t o = 0;
    unsigned char* Cc = (unsigned char*)(p + o); o = align256(o + (size_t)B * NP);
    float2* A   = (float2*)(p + o);              o = align256(o + (size_t)B * NP * sizeof(float2));
    float4* REC = (float4*)(p + o);              o = align256(o + (size_t)total * sizeof(float4));
    float*  kv  = (float*)(p + o);               o = align256(o + (size_t)B * NCLS * CAP * sizeof(float));
    int*   kcnt = (int*)(p + o);

    int gridA = (total + 3) / 4;              // 4 waves / 256-thr block
    score_kernel<<<gridA, 256, 0, stream>>>(det, A, Cc, REC, N, NP, total);
    nms_kernel<<<B * NCLS, 64, 0, stream>>>(A, Cc, REC, kv, kcnt, N, NT, NP);
    rank_out_kernel<<<B * KBLK, 512, 0, stream>>>(kv, kcnt, out);
}